// Round 8
// baseline (638.715 us; speedup 1.0000x reference)
//
#include <hip/hip_runtime.h>
#include <hip/hip_bf16.h>

// ============================================================================
// SelfAttention B=4, N=4096, D=256.  Inputs fp32, OUTPUT fp32.
//
// R8: (a) attn split-K x6 (ragged 21/21/22/21/21/22 kt) -> 768 blocks = 3
// blocks/CU (3 wave-streams per SIMD to fill dependency stalls; LDS
// 47.6KB x 3 = 142.8 <= 160KB).  (b) proj loads W B-frags straight from
// global (L2-resident 384KB) -> zero in-loop barriers.
// Fixed-M softmax (p = exp2(s-16)) as verified in R7.
//
// ws layout (MB): Wt@0 | Q@1 | K@9 | Vt@17 | Obf@25 (5 x 8) | lp@65  ~65.4MB
// ============================================================================

typedef __attribute__((ext_vector_type(8))) short bf16x8;   // MFMA A/B frag (4 VGPR)
typedef __attribute__((ext_vector_type(4))) float f32x4;    // MFMA C/D frag

__device__ __forceinline__ float b2f(ushort u){
  union { uint i; float f; } v; v.i = ((uint)u) << 16; return v.f;
}
__device__ __forceinline__ ushort f2b(float f){             // round-to-nearest-even
  union { float f; uint i; } v; v.f = f;
  uint i = v.i;
  return (ushort)((i + 0x7FFFu + ((i >> 16) & 1u)) >> 16);
}
__device__ __forceinline__ uint pack2(float a, float b){
  return (uint)f2b(a) | ((uint)f2b(b) << 16);
}

// log2(e)/sqrt(256) = 1.4426950408889634/16
#define Q_SCALE 0.0901684400555602f
#define FIXED_M 16.0f
#define NSPLIT  6

// ---------------------------------------------------------------------------
// W transpose + fp32->bf16: dst[e][d] = (bf16)src[d][e], src is 256x256 fp32.
// ---------------------------------------------------------------------------
__global__ __launch_bounds__(256) void transpose_w_kernel(
    const float* __restrict__ Wk, const float* __restrict__ Wq,
    const float* __restrict__ Wv, ushort* __restrict__ Wt){
  __shared__ ushort t[64][72];                 // +8 pad
  const float* src = (blockIdx.y == 0) ? Wk : (blockIdx.y == 1) ? Wq : Wv;
  ushort* dst = Wt + blockIdx.y * 65536;
  int tile = blockIdx.x;
  int tr = tile >> 2, tc = tile & 3;           // 4x4 tiles of 64x64
  int tid = threadIdx.x;
  for (int i = tid; i < 1024; i += 256){       // 64 rows x 16 chunks of 4 floats
    int r = i >> 4, ch = i & 15;
    float4 f = *(const float4*)(src + (tr*64 + r)*256 + tc*64 + ch*4);
    uint2 u; u.x = pack2(f.x, f.y); u.y = pack2(f.z, f.w);
    *(uint2*)&t[r][ch*4] = u;
  }
  __syncthreads();
  for (int i = tid; i < 2048; i += 256){       // 64 cols x 32 row-pairs
    int c = i >> 5, r2 = (i & 31)*2;
    uint v = (uint)t[r2][c] | ((uint)t[r2+1][c] << 16);
    *(uint*)(dst + (tc*64 + c)*256 + tr*64 + r2) = v;  // coalesced 4B stores
  }
}

// ---------------------------------------------------------------------------
// QKV projection: out[n][e] = sum_d x[n][d]*W[d][e] + b[e].  64 rows/block,
// K=256.  W B-frags come straight from global Wt (L2-resident) -> the only
// barrier is after x staging; nt-loop is barrier-free and pipelineable.
// ---------------------------------------------------------------------------
__global__ __launch_bounds__(256) void proj_kernel(
    const float* __restrict__ x, const ushort* __restrict__ Wt,
    const float* __restrict__ bK, const float* __restrict__ bQ,
    const float* __restrict__ bV,
    ushort* __restrict__ Ko, ushort* __restrict__ Qo, ushort* __restrict__ Vt){
  __shared__ ushort xs[64][264];   // A tile (bf16), +8 pad
  int my = blockIdx.y;
  int n0 = blockIdx.x * 64;
  const ushort* wsrc = Wt + my*65536;
  const float* bias  = (my==0) ? bK : (my==1) ? bQ : bV;

  int tid = threadIdx.x;
  int lane = tid & 63, w = tid >> 6, quad = lane >> 4, l16 = lane & 15;

  for (int i = tid; i < 4096; i += 256){       // stage x: 64 rows x 64 f4-chunks
    int r = i >> 6, ch = i & 63;
    float4 f = *(const float4*)(x + (size_t)(n0 + r)*256 + ch*4);
    uint2 u; u.x = pack2(f.x, f.y); u.y = pack2(f.z, f.w);
    *(uint2*)&xs[r][ch*4] = u;
  }
  __syncthreads();

  bf16x8 afr[8];                               // wave's 16 rows, all of K=256
  #pragma unroll
  for (int ks = 0; ks < 8; ks++)
    afr[ks] = *(const bf16x8*)&xs[w*16 + l16][ks*32 + quad*8];

  for (int nt = 0; nt < 16; nt++){             // 16 col-tiles of 16, no barriers
    f32x4 acc = {0.f, 0.f, 0.f, 0.f};
    #pragma unroll
    for (int ks = 0; ks < 8; ks++){
      bf16x8 bfr = *(const bf16x8*)(wsrc + (size_t)(nt*16 + l16)*256 + ks*32 + quad*8);
      acc = __builtin_amdgcn_mfma_f32_16x16x32_bf16(afr[ks], bfr, acc, 0, 0, 0);
    }
    int e = nt*16 + l16;
    float bv = bias[e];
    if (my == 2){                              // V: write transposed Vt[b][e][n]
      int b  = n0 >> 12;
      int nl = (n0 & 4095) + w*16 + quad*4;    // n within batch
      ushort* vb = Vt + (size_t)b*1048576 + (size_t)e*4096 + nl;
      #pragma unroll
      for (int r = 0; r < 4; r++) vb[r] = f2b(acc[r] + bv);
    } else {
      float scale = (my==1) ? Q_SCALE : 1.0f;
      ushort* out = (my==0) ? Ko : Qo;
      #pragma unroll
      for (int r = 0; r < 4; r++){
        int row = n0 + w*16 + quad*4 + r;      // C layout: row=quad*4+r, col=l16
        out[(size_t)row*256 + e] = f2b((acc[r] + bv) * scale);
      }
    }
  }
}

// ---------------------------------------------------------------------------
// Flash attention, ragged split-K x6, 2 q-sets/wave, fixed-M softmax.
// 768 blocks: bx % 24 = (b<<?):  decode b = (bx%24)/6, h = bx%6; qt = bx/24.
// Block = 4 waves x 32 q (128 q/tile).  TK=32, kt in [h*128/6,(h+1)*128/6).
// Writes UNNORMALIZED O-hat + l: h 0 -> O0 (fp32, = d_out),
// h 1..5 -> Obf (bf16, ws).  All partials share scale 2^-16.
// ---------------------------------------------------------------------------
__global__ __launch_bounds__(256, 3) void attn_kernel(
    const ushort* __restrict__ Q, const ushort* __restrict__ K,
    const ushort* __restrict__ Vt,
    float* __restrict__ O0, ushort* __restrict__ Obf, float* __restrict__ lp){
  __shared__ ushort Ks[32][264];   // K tile [key][d]          16.9 KB
  __shared__ ushort Vs[256][40];   // V tile [d][key_local]    20.5 KB
  __shared__ ushort Ps[128][40];   // P round-trip             10.2 KB

  int bx   = blockIdx.x;
  int bh   = bx % 24;
  int b    = bh / NSPLIT;                   // batch 0..3
  int h    = bh % NSPLIT;                   // k-piece 0..5
  int qt   = bx / 24;                       // q-tile 0..31 (128 q each)
  int tid = threadIdx.x, lane = tid & 63, w = tid >> 6;
  int quad = lane >> 4, l16 = lane & 15;

  const ushort* Qb = Q  + (size_t)(b*4096 + qt*128)*256;
  const ushort* Kb = K  + (size_t)b*4096*256;
  const ushort* Vb = Vt + (size_t)b*256*4096;

  bf16x8 qf[2][8];                 // A-frags, 2 sets: rows w*32+s*16+l16
  #pragma unroll
  for (int s = 0; s < 2; s++)
    #pragma unroll
    for (int ks = 0; ks < 8; ks++)
      qf[s][ks] = *(const bf16x8*)(Qb + (size_t)(w*32 + s*16 + l16)*256 + ks*32 + quad*8);

  f32x4 of[2][16];                 // O accumulators
  #pragma unroll
  for (int s = 0; s < 2; s++)
    #pragma unroll
    for (int dt = 0; dt < 16; dt++) of[s][dt] = (f32x4){0.f, 0.f, 0.f, 0.f};
  float l_i[2][4];                 // per-LANE partial sums (2 cols each)
  #pragma unroll
  for (int s = 0; s < 2; s++)
    #pragma unroll
    for (int r = 0; r < 4; r++) l_i[s][r] = 0.f;

  int kt0 = (h*128)/NSPLIT, kt1 = ((h+1)*128)/NSPLIT;   // ragged partition
  for (int kt = kt0; kt < kt1; kt++){
    __syncthreads();                         // protect Ks/Vs from prev reads
    for (int i = tid; i < 1024; i += 256){   // K tile: 32 rows x 32 chunks
      int r = i >> 5, ch = i & 31;
      *(uint4*)&Ks[r][ch*8] = *(const uint4*)(Kb + (size_t)(kt*32 + r)*256 + ch*8);
    }
    for (int i = tid; i < 1024; i += 256){   // V tile: 256 d x 4 chunks
      int d = i >> 2, ch = i & 3;
      *(uint4*)&Vs[d][ch*8] = *(const uint4*)(Vb + (size_t)d*4096 + kt*32 + ch*8);
    }
    __syncthreads();

    // ---- S = Qhat @ K^T : each Ks B-frag feeds both q-sets ---------------
    f32x4 sf[2][2];                          // [set][nt]
    #pragma unroll
    for (int s = 0; s < 2; s++)
      #pragma unroll
      for (int nt = 0; nt < 2; nt++) sf[s][nt] = (f32x4){0.f, 0.f, 0.f, 0.f};
    #pragma unroll
    for (int nt = 0; nt < 2; nt++)
      #pragma unroll
      for (int ks = 0; ks < 8; ks++){
        bf16x8 bfr = *(const bf16x8*)&Ks[nt*16 + l16][ks*32 + quad*8];
        sf[0][nt] = __builtin_amdgcn_mfma_f32_16x16x32_bf16(qf[0][ks], bfr, sf[0][nt], 0,0,0);
        sf[1][nt] = __builtin_amdgcn_mfma_f32_16x16x32_bf16(qf[1][ks], bfr, sf[1][nt], 0,0,0);
      }

    // ---- fixed-M softmax: p = exp2(s - 16); no cross-lane, no rescale ----
    #pragma unroll
    for (int s = 0; s < 2; s++){
      #pragma unroll
      for (int r = 0; r < 4; r++){
        float p0 = exp2f(sf[s][0][r] - FIXED_M);
        float p1 = exp2f(sf[s][1][r] - FIXED_M);
        l_i[s][r] += p0 + p1;
        Ps[w*32 + s*16 + quad*4 + r][l16]      = f2b(p0);
        Ps[w*32 + s*16 + quad*4 + r][16 + l16] = f2b(p1);
      }
    }
    __threadfence_block();                   // order LDS write -> cross-lane read

    // ---- PV: each Vs B-frag feeds both q-sets ----------------------------
    bf16x8 pf0 = *(const bf16x8*)&Ps[w*32 +      l16][quad*8];
    bf16x8 pf1 = *(const bf16x8*)&Ps[w*32 + 16 + l16][quad*8];
    #pragma unroll
    for (int dt = 0; dt < 16; dt++){
      bf16x8 vf = *(const bf16x8*)&Vs[dt*16 + l16][quad*8]; // B[k][n]=V[key][d]
      of[0][dt] = __builtin_amdgcn_mfma_f32_16x16x32_bf16(pf0, vf, of[0][dt], 0, 0, 0);
      of[1][dt] = __builtin_amdgcn_mfma_f32_16x16x32_bf16(pf1, vf, of[1][dt], 0, 0, 0);
    }
  }

  // ---- one l reduction for the whole kernel ------------------------------
  #pragma unroll
  for (int s = 0; s < 2; s++)
    #pragma unroll
    for (int r = 0; r < 4; r++){
      float rs = l_i[s][r];
      #pragma unroll
      for (int msk = 1; msk < 16; msk <<= 1) rs += __shfl_xor(rs, msk, 16);
      l_i[s][r] = rs;
    }

  // ---- epilogue: write unnormalized O-hat + l partials -------------------
  #pragma unroll
  for (int s = 0; s < 2; s++){
    int gq0 = b*4096 + qt*128 + w*32 + s*16 + quad*4;  // global q row, r=0
    if (l16 == 0){
      #pragma unroll
      for (int r = 0; r < 4; r++)
        lp[(size_t)h*16384 + gq0 + r] = l_i[s][r];
    }
    if (h == 0){
      #pragma unroll
      for (int dt = 0; dt < 16; dt++)
        #pragma unroll
        for (int r = 0; r < 4; r++)
          O0[(size_t)(gq0 + r)*256 + dt*16 + l16] = of[s][dt][r];
    } else {
      ushort* Oh = Obf + (size_t)(h - 1)*16384*256;
      #pragma unroll
      for (int dt = 0; dt < 16; dt++)
        #pragma unroll
        for (int r = 0; r < 4; r++)
          Oh[(size_t)(gq0 + r)*256 + dt*16 + l16] = f2b(of[s][dt][r]);
    }
  }
}

// ---------------------------------------------------------------------------
// Merge the 6 split-K partials (all on scale 2^-16), in place over O0.
// out = (O0hat + sum_h Ohat_h) / sum_h l_h.
// ---------------------------------------------------------------------------
__global__ __launch_bounds__(256) void merge_kernel(
    float* __restrict__ O0, const ushort* __restrict__ Obf,
    const float* __restrict__ lp){
  int t   = blockIdx.x*256 + threadIdx.x;    // 0 .. 1048575
  int row = t >> 6;                          // 16384 q rows
  int c   = (t & 63) * 4;
  float den = 0.f;
  #pragma unroll
  for (int h = 0; h < NSPLIT; h++) den += lp[(size_t)h*16384 + row];
  float rden = 1.0f / den;
  size_t idx = (size_t)row*256 + c;
  float4 acc = *(float4*)&O0[idx];
  #pragma unroll
  for (int h = 1; h < NSPLIT; h++){
    ushort4 oh = *(const ushort4*)&Obf[(size_t)(h-1)*16384*256 + idx];
    acc.x += b2f(oh.x); acc.y += b2f(oh.y);
    acc.z += b2f(oh.z); acc.w += b2f(oh.w);
  }
  acc.x *= rden; acc.y *= rden; acc.z *= rden; acc.w *= rden;
  *(float4*)&O0[idx] = acc;
}

// ---------------------------------------------------------------------------
extern "C" void kernel_launch(void* const* d_in, const int* in_sizes, int n_in,
                              void* d_out, int out_size, void* d_ws, size_t ws_size,
                              hipStream_t stream){
  const float* x  = (const float*)d_in[0];
  const float* Wk = (const float*)d_in[1];
  const float* bk = (const float*)d_in[2];
  const float* Wq = (const float*)d_in[3];
  const float* bq = (const float*)d_in[4];
  const float* Wv = (const float*)d_in[5];
  const float* bv = (const float*)d_in[6];

  char* ws = (char*)d_ws;
  ushort* Wt  = (ushort*)(ws);                       // 3 x 256 x 256 bf16
  ushort* Qb  = (ushort*)(ws + (size_t)1*(1u<<20));  // 16384 x 256 bf16 (8MB)
  ushort* Kb  = (ushort*)(ws + (size_t)9*(1u<<20));
  ushort* Vtb = (ushort*)(ws + (size_t)17*(1u<<20)); // 4 x 256 x 4096 bf16
  ushort* Obf = (ushort*)(ws + (size_t)25*(1u<<20)); // 5 x 16384 x 256 bf16
  float*  lp  = (float*)(ws + (size_t)65*(1u<<20));  // [6][16384] fp32

  hipLaunchKernelGGL(transpose_w_kernel, dim3(16, 3), dim3(256), 0, stream,
                     Wk, Wq, Wv, Wt);
  hipLaunchKernelGGL(proj_kernel, dim3(256, 3), dim3(256), 0, stream,
                     x, Wt, bk, bq, bv, Kb, Qb, Vtb);
  hipLaunchKernelGGL(attn_kernel, dim3(768), dim3(256), 0, stream,
                     Qb, Kb, Vtb, (float*)d_out, Obf, lp);
  hipLaunchKernelGGL(merge_kernel, dim3(4096), dim3(256), 0, stream,
                     (float*)d_out, Obf, lp);
}

// Round 9
// 344.642 us; speedup vs baseline: 1.8533x; 1.8533x over previous
//
#include <hip/hip_runtime.h>
#include <hip/hip_bf16.h>

// ============================================================================
// SelfAttention B=4, N=4096, D=256.  Inputs fp32, OUTPUT fp32.
//
// R9: barrier-free attention kt-loop.  K and Vt fragments are loaded
// STRAIGHT FROM GLOBAL (L2-resident, 16B/lane aligned) — no LDS staging, no
// __syncthreads in the loop.  LDS holds only the wave-private P round-trip.
// The compiler can now overlap kt+1 fragment loads with kt's PV MFMAs
// (fine-grained vmcnt pipelining the 2-barrier structure forbade).
// R8 lesson: this tile is register-bound at 2 waves/SIMD — launch_bounds
// (256,2); (256,3) spills the 128-reg accumulator (2.1GB scratch traffic).
// Fixed-M softmax (p = exp2(s-16)) as verified in R7.  Split-K x4.
//
// ws layout (MB): Wt@0 | Q@1 | K@10 | Vt@19 | Obf@28 (3 x 8.4) | lp@54
// ============================================================================

typedef __attribute__((ext_vector_type(8))) short bf16x8;   // MFMA A/B frag (4 VGPR)
typedef __attribute__((ext_vector_type(4))) float f32x4;    // MFMA C/D frag

__device__ __forceinline__ float b2f(ushort u){
  union { uint i; float f; } v; v.i = ((uint)u) << 16; return v.f;
}
__device__ __forceinline__ ushort f2b(float f){             // round-to-nearest-even
  union { float f; uint i; } v; v.f = f;
  uint i = v.i;
  return (ushort)((i + 0x7FFFu + ((i >> 16) & 1u)) >> 16);
}
__device__ __forceinline__ uint pack2(float a, float b){
  return (uint)f2b(a) | ((uint)f2b(b) << 16);
}

// log2(e)/sqrt(256) = 1.4426950408889634/16
#define Q_SCALE 0.0901684400555602f
#define FIXED_M 16.0f

// ---------------------------------------------------------------------------
// W transpose + fp32->bf16: dst[e][d] = (bf16)src[d][e], src is 256x256 fp32.
// ---------------------------------------------------------------------------
__global__ __launch_bounds__(256) void transpose_w_kernel(
    const float* __restrict__ Wk, const float* __restrict__ Wq,
    const float* __restrict__ Wv, ushort* __restrict__ Wt){
  __shared__ ushort t[64][72];                 // +8 pad
  const float* src = (blockIdx.y == 0) ? Wk : (blockIdx.y == 1) ? Wq : Wv;
  ushort* dst = Wt + blockIdx.y * 65536;
  int tile = blockIdx.x;
  int tr = tile >> 2, tc = tile & 3;           // 4x4 tiles of 64x64
  int tid = threadIdx.x;
  for (int i = tid; i < 1024; i += 256){       // 64 rows x 16 chunks of 4 floats
    int r = i >> 4, ch = i & 15;
    float4 f = *(const float4*)(src + (tr*64 + r)*256 + tc*64 + ch*4);
    uint2 u; u.x = pack2(f.x, f.y); u.y = pack2(f.z, f.w);
    *(uint2*)&t[r][ch*4] = u;
  }
  __syncthreads();
  for (int i = tid; i < 2048; i += 256){       // 64 cols x 32 row-pairs
    int c = i >> 5, r2 = (i & 31)*2;
    uint v = (uint)t[r2][c] | ((uint)t[r2+1][c] << 16);
    *(uint*)(dst + (tc*64 + c)*256 + tr*64 + r2) = v;  // coalesced 4B stores
  }
}

// ---------------------------------------------------------------------------
// QKV projection (R7-proven version): out[n][e] = sum_d x[n][d]*W[d][e]+b[e].
// blockIdx.y: 0=K, 1=Q (scaled), 2=V->Vt transposed.  64 rows/block, K=256.
// ---------------------------------------------------------------------------
__global__ __launch_bounds__(256) void proj_kernel(
    const float* __restrict__ x, const ushort* __restrict__ Wt,
    const float* __restrict__ bK, const float* __restrict__ bQ,
    const float* __restrict__ bV,
    ushort* __restrict__ Ko, ushort* __restrict__ Qo, ushort* __restrict__ Vt){
  __shared__ ushort xs[64][264];   // A tile (bf16), +8 pad
  __shared__ ushort wt[16][264];   // B tile (Wt rows e, cols d)
  int my = blockIdx.y;
  int n0 = blockIdx.x * 64;
  const ushort* wsrc = Wt + my*65536;
  const float* bias  = (my==0) ? bK : (my==1) ? bQ : bV;

  int tid = threadIdx.x;
  int lane = tid & 63, w = tid >> 6, quad = lane >> 4, l16 = lane & 15;

  for (int i = tid; i < 4096; i += 256){       // stage x: 64 rows x 64 f4-chunks
    int r = i >> 6, ch = i & 63;
    float4 f = *(const float4*)(x + (size_t)(n0 + r)*256 + ch*4);
    uint2 u; u.x = pack2(f.x, f.y); u.y = pack2(f.z, f.w);
    *(uint2*)&xs[r][ch*4] = u;
  }
  __syncthreads();

  bf16x8 afr[8];                               // wave's 16 rows, all of K=256
  #pragma unroll
  for (int ks = 0; ks < 8; ks++)
    afr[ks] = *(const bf16x8*)&xs[w*16 + l16][ks*32 + quad*8];

  for (int nt = 0; nt < 16; nt++){             // 16 col-tiles of 16
    __syncthreads();
    for (int i = tid; i < 512; i += 256){      // stage Wt rows nt*16..+16
      int r = i >> 5, ch = i & 31;
      *(uint4*)&wt[r][ch*8] = *(const uint4*)(wsrc + (nt*16 + r)*256 + ch*8);
    }
    __syncthreads();
    f32x4 acc = {0.f, 0.f, 0.f, 0.f};
    #pragma unroll
    for (int ks = 0; ks < 8; ks++){
      bf16x8 bfr = *(const bf16x8*)&wt[l16][ks*32 + quad*8];
      acc = __builtin_amdgcn_mfma_f32_16x16x32_bf16(afr[ks], bfr, acc, 0, 0, 0);
    }
    int e = nt*16 + l16;
    float bv = bias[e];
    if (my == 2){                              // V: write transposed Vt[b][e][n]
      int b  = n0 >> 12;
      int nl = (n0 & 4095) + w*16 + quad*4;    // n within batch
      ushort* vb = Vt + (size_t)b*1048576 + (size_t)e*4096 + nl;
      #pragma unroll
      for (int r = 0; r < 4; r++) vb[r] = f2b(acc[r] + bv);
    } else {
      float scale = (my==1) ? Q_SCALE : 1.0f;
      ushort* out = (my==0) ? Ko : Qo;
      #pragma unroll
      for (int r = 0; r < 4; r++){
        int row = n0 + w*16 + quad*4 + r;      // C layout: row=quad*4+r, col=l16
        out[(size_t)row*256 + e] = f2b((acc[r] + bv) * scale);
      }
    }
  }
}

// ---------------------------------------------------------------------------
// Flash attention, split-K x4, 2 q-sets/wave, fixed-M softmax, BARRIER-FREE.
// 512 blocks: bx & 15 = (b<<2)|half ; bx >> 4 = qt 0..31 (128 q/tile).
// K/Vt fragments load straight from global (L2-resident); LDS = Ps only
// (wave-private rows -> no __syncthreads anywhere in the kt loop).
// Writes UNNORMALIZED O-hat + l: half 0 -> O0 (fp32, = d_out),
// halves 1..3 -> Obf (bf16, ws).  All partials share scale 2^-16.
// ---------------------------------------------------------------------------
__global__ __launch_bounds__(256, 2) void attn_kernel(
    const ushort* __restrict__ Q, const ushort* __restrict__ K,
    const ushort* __restrict__ Vt,
    float* __restrict__ O0, ushort* __restrict__ Obf, float* __restrict__ lp){
  __shared__ ushort Ps[128][40];   // P round-trip, wave-private rows  10.2 KB

  int bx   = blockIdx.x;
  int bh   = bx & 15;
  int b    = bh >> 2;                       // batch 0..3
  int half = bh & 3;                        // k-quarter 0..3
  int qt   = bx >> 4;                       // q-tile 0..31 (128 q each)
  int tid = threadIdx.x, lane = tid & 63, w = tid >> 6;
  int quad = lane >> 4, l16 = lane & 15;

  const ushort* Qb = Q  + (size_t)(b*4096 + qt*128)*256;
  const ushort* Kb = K  + (size_t)b*4096*256;
  const ushort* Vb = Vt + (size_t)b*256*4096;

  bf16x8 qf[2][8];                 // A-frags, 2 sets: rows w*32+s*16+l16
  #pragma unroll
  for (int s = 0; s < 2; s++)
    #pragma unroll
    for (int ks = 0; ks < 8; ks++)
      qf[s][ks] = *(const bf16x8*)(Qb + (size_t)(w*32 + s*16 + l16)*256 + ks*32 + quad*8);

  f32x4 of[2][16];                 // O accumulators
  #pragma unroll
  for (int s = 0; s < 2; s++)
    #pragma unroll
    for (int dt = 0; dt < 16; dt++) of[s][dt] = (f32x4){0.f, 0.f, 0.f, 0.f};
  float l_i[2][4];                 // per-LANE partial sums (2 cols each)
  #pragma unroll
  for (int s = 0; s < 2; s++)
    #pragma unroll
    for (int r = 0; r < 4; r++) l_i[s][r] = 0.f;

  // per-lane base pointers for direct-from-global fragments
  const ushort* Kl = Kb + (size_t)l16*256 + quad*8;   // + kt*32*256 + nt*16*256 + ks*32
  const ushort* Vl = Vb + (size_t)l16*4096 + quad*8;  // + dt*16*4096 + kt*32

  int kt0 = half * 32;
  for (int kt = kt0; kt < kt0 + 32; kt++){
    // ---- S = Qhat @ K^T : B-frags straight from global (L2) --------------
    f32x4 sf[2][2];                          // [set][nt]
    #pragma unroll
    for (int s = 0; s < 2; s++)
      #pragma unroll
      for (int nt = 0; nt < 2; nt++) sf[s][nt] = (f32x4){0.f, 0.f, 0.f, 0.f};
    const ushort* Kkt = Kl + (size_t)kt*32*256;
    #pragma unroll
    for (int nt = 0; nt < 2; nt++)
      #pragma unroll
      for (int ks = 0; ks < 8; ks++){
        bf16x8 bfr = *(const bf16x8*)(Kkt + (size_t)nt*16*256 + ks*32);
        sf[0][nt] = __builtin_amdgcn_mfma_f32_16x16x32_bf16(qf[0][ks], bfr, sf[0][nt], 0,0,0);
        sf[1][nt] = __builtin_amdgcn_mfma_f32_16x16x32_bf16(qf[1][ks], bfr, sf[1][nt], 0,0,0);
      }

    // ---- fixed-M softmax: p = exp2(s - 16); no cross-lane, no rescale ----
    #pragma unroll
    for (int s = 0; s < 2; s++){
      #pragma unroll
      for (int r = 0; r < 4; r++){
        float p0 = exp2f(sf[s][0][r] - FIXED_M);
        float p1 = exp2f(sf[s][1][r] - FIXED_M);
        l_i[s][r] += p0 + p1;
        Ps[w*32 + s*16 + quad*4 + r][l16]      = f2b(p0);
        Ps[w*32 + s*16 + quad*4 + r][16 + l16] = f2b(p1);
      }
    }
    // wave-private LDS round-trip: compiler orders ds_write -> ds_read via
    // lgkmcnt (same object); no barrier, vmcnt pipeline stays live.

    // ---- PV: V B-frags straight from global (L2) -------------------------
    bf16x8 pf0 = *(const bf16x8*)&Ps[w*32 +      l16][quad*8];
    bf16x8 pf1 = *(const bf16x8*)&Ps[w*32 + 16 + l16][quad*8];
    const ushort* Vkt = Vl + (size_t)kt*32;
    #pragma unroll
    for (int dt = 0; dt < 16; dt++){
      bf16x8 vf = *(const bf16x8*)(Vkt + (size_t)dt*16*4096); // B[k][n]=V[key][d]
      of[0][dt] = __builtin_amdgcn_mfma_f32_16x16x32_bf16(pf0, vf, of[0][dt], 0, 0, 0);
      of[1][dt] = __builtin_amdgcn_mfma_f32_16x16x32_bf16(pf1, vf, of[1][dt], 0, 0, 0);
    }
  }

  // ---- one l reduction for the whole kernel ------------------------------
  #pragma unroll
  for (int s = 0; s < 2; s++)
    #pragma unroll
    for (int r = 0; r < 4; r++){
      float rs = l_i[s][r];
      #pragma unroll
      for (int msk = 1; msk < 16; msk <<= 1) rs += __shfl_xor(rs, msk, 16);
      l_i[s][r] = rs;
    }

  // ---- epilogue: write unnormalized O-hat + l partials -------------------
  #pragma unroll
  for (int s = 0; s < 2; s++){
    int gq0 = b*4096 + qt*128 + w*32 + s*16 + quad*4;  // global q row, r=0
    if (l16 == 0){
      #pragma unroll
      for (int r = 0; r < 4; r++)
        lp[(size_t)half*16384 + gq0 + r] = l_i[s][r];
    }
    if (half == 0){
      #pragma unroll
      for (int dt = 0; dt < 16; dt++)
        #pragma unroll
        for (int r = 0; r < 4; r++)
          O0[(size_t)(gq0 + r)*256 + dt*16 + l16] = of[s][dt][r];
    } else {
      ushort* Oh = Obf + (size_t)(half - 1)*16384*256;
      #pragma unroll
      for (int dt = 0; dt < 16; dt++)
        #pragma unroll
        for (int r = 0; r < 4; r++)
          Oh[(size_t)(gq0 + r)*256 + dt*16 + l16] = f2b(of[s][dt][r]);
    }
  }
}

// ---------------------------------------------------------------------------
// Merge the 4 split-K partials (all on scale 2^-16), in place over O0.
// out = (O0hat + sum_h Ohat_h) / sum_h l_h.
// ---------------------------------------------------------------------------
__global__ __launch_bounds__(256) void merge_kernel(
    float* __restrict__ O0, const ushort* __restrict__ Obf,
    const float* __restrict__ lp){
  int t   = blockIdx.x*256 + threadIdx.x;    // 0 .. 1048575
  int row = t >> 6;                          // 16384 q rows
  int c   = (t & 63) * 4;
  float den = lp[row] + lp[16384 + row] + lp[2*16384 + row] + lp[3*16384 + row];
  float rden = 1.0f / den;
  size_t idx = (size_t)row*256 + c;
  float4 acc = *(float4*)&O0[idx];
  #pragma unroll
  for (int h = 1; h < 4; h++){
    ushort4 oh = *(const ushort4*)&Obf[(size_t)(h-1)*16384*256 + idx];
    acc.x += b2f(oh.x); acc.y += b2f(oh.y);
    acc.z += b2f(oh.z); acc.w += b2f(oh.w);
  }
  acc.x *= rden; acc.y *= rden; acc.z *= rden; acc.w *= rden;
  *(float4*)&O0[idx] = acc;
}

// ---------------------------------------------------------------------------
extern "C" void kernel_launch(void* const* d_in, const int* in_sizes, int n_in,
                              void* d_out, int out_size, void* d_ws, size_t ws_size,
                              hipStream_t stream){
  const float* x  = (const float*)d_in[0];
  const float* Wk = (const float*)d_in[1];
  const float* bk = (const float*)d_in[2];
  const float* Wq = (const float*)d_in[3];
  const float* bq = (const float*)d_in[4];
  const float* Wv = (const float*)d_in[5];
  const float* bv = (const float*)d_in[6];

  char* ws = (char*)d_ws;
  ushort* Wt  = (ushort*)(ws);                       // 3 x 256 x 256 bf16
  ushort* Qb  = (ushort*)(ws + (size_t)1*(1u<<20));  // 16384 x 256 bf16
  ushort* Kb  = (ushort*)(ws + (size_t)10*(1u<<20));
  ushort* Vtb = (ushort*)(ws + (size_t)19*(1u<<20)); // 4 x 256 x 4096 bf16
  ushort* Obf = (ushort*)(ws + (size_t)28*(1u<<20)); // 3 x 16384 x 256 bf16
  float*  lp  = (float*)(ws + (size_t)54*(1u<<20));  // [4][16384] fp32

  hipLaunchKernelGGL(transpose_w_kernel, dim3(16, 3), dim3(256), 0, stream,
                     Wk, Wq, Wv, Wt);
  hipLaunchKernelGGL(proj_kernel, dim3(256, 3), dim3(256), 0, stream,
                     x, Wt, bk, bq, bv, Kb, Qb, Vtb);
  hipLaunchKernelGGL(attn_kernel, dim3(512), dim3(256), 0, stream,
                     Qb, Kb, Vtb, (float*)d_out, Obf, lp);
  hipLaunchKernelGGL(merge_kernel, dim3(4096), dim3(256), 0, stream,
                     (float*)d_out, Obf, lp);
}

// Round 10
// 232.811 us; speedup vs baseline: 2.7435x; 1.4803x over previous
//
#include <hip/hip_runtime.h>
#include <hip/hip_bf16.h>

// ============================================================================
// SelfAttention B=4, N=4096, D=256.  Inputs fp32, OUTPUT fp32.
//
// R10: async double-buffered staging via global_load_lds (16B), ONE barrier
// per kt: issue kt+1's K/V tiles at top of iteration kt -> they drain at the
// end-of-kt barrier after ~2000 cyc in flight (vs R7's zero-overlap drain).
// K/V LDS buffers are UNPADDED + XOR-swizzled (global-source permutation at
// stage time; read-side verified 2-accesses-per-bank-group per quarter-wave).
// Base structure = R7 (split-K x4, 2 q-sets/wave, fixed-M softmax, 512 blk).
// R8/R9 lessons: VGPR-capped at 2 waves/SIMD (no 3rd block, no reg-prefetch);
// LDS-bypass = latency death.  proj = R8's barrier-free W-direct variant
// (correctness-validated in R8).
//
// ws layout (MB): Wt@0 | Q@1 | K@10 | Vt@19 | Obf@28 (3 x 8.4) | lp@54
// ============================================================================

typedef __attribute__((ext_vector_type(8))) short bf16x8;   // MFMA A/B frag (4 VGPR)
typedef __attribute__((ext_vector_type(4))) float f32x4;    // MFMA C/D frag

__device__ __forceinline__ float b2f(ushort u){
  union { uint i; float f; } v; v.i = ((uint)u) << 16; return v.f;
}
__device__ __forceinline__ ushort f2b(float f){             // round-to-nearest-even
  union { float f; uint i; } v; v.f = f;
  uint i = v.i;
  return (ushort)((i + 0x7FFFu + ((i >> 16) & 1u)) >> 16);
}
__device__ __forceinline__ uint pack2(float a, float b){
  return (uint)f2b(a) | ((uint)f2b(b) << 16);
}

// async 16B global -> LDS (DMA; LDS dest = wave-uniform base + lane*16)
__device__ __forceinline__ void gl_lds16(const ushort* g, ushort* l){
  __builtin_amdgcn_global_load_lds(
      (const __attribute__((address_space(1))) uint*)g,
      (__attribute__((address_space(3))) uint*)l, 16, 0, 0);
}

// log2(e)/sqrt(256) = 1.4426950408889634/16
#define Q_SCALE 0.0901684400555602f
#define FIXED_M 16.0f

// ---------------------------------------------------------------------------
// W transpose + fp32->bf16: dst[e][d] = (bf16)src[d][e], src is 256x256 fp32.
// ---------------------------------------------------------------------------
__global__ __launch_bounds__(256) void transpose_w_kernel(
    const float* __restrict__ Wk, const float* __restrict__ Wq,
    const float* __restrict__ Wv, ushort* __restrict__ Wt){
  __shared__ ushort t[64][72];                 // +8 pad
  const float* src = (blockIdx.y == 0) ? Wk : (blockIdx.y == 1) ? Wq : Wv;
  ushort* dst = Wt + blockIdx.y * 65536;
  int tile = blockIdx.x;
  int tr = tile >> 2, tc = tile & 3;           // 4x4 tiles of 64x64
  int tid = threadIdx.x;
  for (int i = tid; i < 1024; i += 256){       // 64 rows x 16 chunks of 4 floats
    int r = i >> 4, ch = i & 15;
    float4 f = *(const float4*)(src + (tr*64 + r)*256 + tc*64 + ch*4);
    uint2 u; u.x = pack2(f.x, f.y); u.y = pack2(f.z, f.w);
    *(uint2*)&t[r][ch*4] = u;
  }
  __syncthreads();
  for (int i = tid; i < 2048; i += 256){       // 64 cols x 32 row-pairs
    int c = i >> 5, r2 = (i & 31)*2;
    uint v = (uint)t[r2][c] | ((uint)t[r2+1][c] << 16);
    *(uint*)(dst + (tc*64 + c)*256 + tr*64 + r2) = v;  // coalesced 4B stores
  }
}

// ---------------------------------------------------------------------------
// QKV projection (R8 barrier-free variant, correctness-validated in R8):
// W B-frags straight from global Wt (L2-resident, 384KB); only barrier is
// after x staging.  blockIdx.y: 0=K, 1=Q (scaled), 2=V->Vt transposed.
// ---------------------------------------------------------------------------
__global__ __launch_bounds__(256) void proj_kernel(
    const float* __restrict__ x, const ushort* __restrict__ Wt,
    const float* __restrict__ bK, const float* __restrict__ bQ,
    const float* __restrict__ bV,
    ushort* __restrict__ Ko, ushort* __restrict__ Qo, ushort* __restrict__ Vt){
  __shared__ ushort xs[64][264];   // A tile (bf16), +8 pad
  int my = blockIdx.y;
  int n0 = blockIdx.x * 64;
  const ushort* wsrc = Wt + my*65536;
  const float* bias  = (my==0) ? bK : (my==1) ? bQ : bV;

  int tid = threadIdx.x;
  int lane = tid & 63, w = tid >> 6, quad = lane >> 4, l16 = lane & 15;

  for (int i = tid; i < 4096; i += 256){       // stage x: 64 rows x 64 f4-chunks
    int r = i >> 6, ch = i & 63;
    float4 f = *(const float4*)(x + (size_t)(n0 + r)*256 + ch*4);
    uint2 u; u.x = pack2(f.x, f.y); u.y = pack2(f.z, f.w);
    *(uint2*)&xs[r][ch*4] = u;
  }
  __syncthreads();

  bf16x8 afr[8];                               // wave's 16 rows, all of K=256
  #pragma unroll
  for (int ks = 0; ks < 8; ks++)
    afr[ks] = *(const bf16x8*)&xs[w*16 + l16][ks*32 + quad*8];

  for (int nt = 0; nt < 16; nt++){             // 16 col-tiles of 16, no barriers
    f32x4 acc = {0.f, 0.f, 0.f, 0.f};
    #pragma unroll
    for (int ks = 0; ks < 8; ks++){
      bf16x8 bfr = *(const bf16x8*)(wsrc + (size_t)(nt*16 + l16)*256 + ks*32 + quad*8);
      acc = __builtin_amdgcn_mfma_f32_16x16x32_bf16(afr[ks], bfr, acc, 0, 0, 0);
    }
    int e = nt*16 + l16;
    float bv = bias[e];
    if (my == 2){                              // V: write transposed Vt[b][e][n]
      int b  = n0 >> 12;
      int nl = (n0 & 4095) + w*16 + quad*4;    // n within batch
      ushort* vb = Vt + (size_t)b*1048576 + (size_t)e*4096 + nl;
      #pragma unroll
      for (int r = 0; r < 4; r++) vb[r] = f2b(acc[r] + bv);
    } else {
      float scale = (my==1) ? Q_SCALE : 1.0f;
      ushort* out = (my==0) ? Ko : Qo;
      #pragma unroll
      for (int r = 0; r < 4; r++){
        int row = n0 + w*16 + quad*4 + r;      // C layout: row=quad*4+r, col=l16
        out[(size_t)row*256 + e] = f2b((acc[r] + bv) * scale);
      }
    }
  }
}

// ---------------------------------------------------------------------------
// Flash attention, split-K x4, 2 q-sets/wave, fixed-M softmax, async dbuf.
// 512 blocks: bx & 15 = (b<<2)|half ; bx >> 4 = qt 0..31 (128 q/tile).
// kt loop: stage(kt+1 -> buf[nxt]) async; compute(kt) on buf[cur]; ONE
// __syncthreads (drains prefetch, fences buffer swap).
// LDS: Kbuf 2x16KB (rows 512B, chunk g = slot ^ (row&7) swizzle),
//      Vbuf 2x16KB (128B superrows: slot' = (4*(d&1)+c) ^ ((d>>1)&7)),
//      Ps 10.2KB (wave-private round-trip, padded).
// Writes UNNORMALIZED O-hat + l: half 0 -> O0 (fp32, = d_out),
// halves 1..3 -> Obf (bf16, ws).  All partials share scale 2^-16.
// ---------------------------------------------------------------------------
__global__ __launch_bounds__(256, 2) void attn_kernel(
    const ushort* __restrict__ Q, const ushort* __restrict__ K,
    const ushort* __restrict__ Vt,
    float* __restrict__ O0, ushort* __restrict__ Obf, float* __restrict__ lp){
  __shared__ ushort Kbuf[2][8192];   // 32 keys x 256 d, unpadded+swizzled
  __shared__ ushort Vbuf[2][8192];   // 256 d x 32 keys, unpadded+swizzled
  __shared__ ushort Ps[128][40];     // P round-trip, wave-private rows

  int bx   = blockIdx.x;
  int bh   = bx & 15;
  int b    = bh >> 2;                       // batch 0..3
  int half = bh & 3;                        // k-quarter 0..3
  int qt   = bx >> 4;                       // q-tile 0..31 (128 q each)
  int tid = threadIdx.x, lane = tid & 63, w = tid >> 6;
  int quad = lane >> 4, l16 = lane & 15;

  const ushort* Qb = Q  + (size_t)(b*4096 + qt*128)*256;
  const ushort* Kb = K  + (size_t)b*4096*256;
  const ushort* Vb = Vt + (size_t)b*256*4096;

  // ---- staging lane->global offset precompute (swizzled) -----------------
  int kOff[4], vOff[4];
  #pragma unroll
  for (int i = 0; i < 4; i++){
    int off16 = (w*4 + i)*64 + lane;         // 16B unit within 16KB tile
    int krow = off16 >> 5, ks_ = off16 & 31;
    int g    = ks_ ^ (krow & 7);             // K swizzle: chunk stored at slot
    kOff[i]  = krow*256 + g*8;               // ushort offset in K global tile
    int sr = off16 >> 3, sl = off16 & 7;     // V: 128B superrow, 16B slot
    int xv = sl ^ (sr & 7);
    int d  = sr*2 + ((xv >> 2) & 1), c = xv & 3;
    vOff[i] = d*4096 + c*8;                  // ushort offset (Vt row stride 4096)
  }
  // compute-side swizzled read offsets
  int m7 = l16 & 7;
  int kslot[8];
  #pragma unroll
  for (int ks = 0; ks < 8; ks++) kslot[ks] = ((ks*4 + quad) ^ m7) * 8;
  int vlane = (((l16 >> 1)*8) + (((l16 & 1)*4 + quad) ^ (l16 >> 1))) * 8;

  bf16x8 qf[2][8];                 // A-frags, 2 sets: rows w*32+s*16+l16
  #pragma unroll
  for (int s = 0; s < 2; s++)
    #pragma unroll
    for (int ks = 0; ks < 8; ks++)
      qf[s][ks] = *(const bf16x8*)(Qb + (size_t)(w*32 + s*16 + l16)*256 + ks*32 + quad*8);

  f32x4 of[2][16];                 // O accumulators
  #pragma unroll
  for (int s = 0; s < 2; s++)
    #pragma unroll
    for (int dt = 0; dt < 16; dt++) of[s][dt] = (f32x4){0.f, 0.f, 0.f, 0.f};
  float l_i[2][4];                 // per-LANE partial sums (2 cols each)
  #pragma unroll
  for (int s = 0; s < 2; s++)
    #pragma unroll
    for (int r = 0; r < 4; r++) l_i[s][r] = 0.f;

  int kt0 = half * 32, kt1 = kt0 + 32;

  // ---- prologue: stage kt0 into buf 0, drain ----------------------------
  #pragma unroll
  for (int i = 0; i < 4; i++){
    gl_lds16(Kb + (size_t)kt0*8192 + kOff[i], &Kbuf[0][(w*4 + i)*512]);
    gl_lds16(Vb + (size_t)kt0*32   + vOff[i], &Vbuf[0][(w*4 + i)*512]);
  }
  __syncthreads();

  int cur = 0;
  for (int kt = kt0; kt < kt1; kt++){
    int nxt = cur ^ 1;
    if (kt + 1 < kt1){                       // async prefetch kt+1 -> buf[nxt]
      #pragma unroll
      for (int i = 0; i < 4; i++){
        gl_lds16(Kb + (size_t)(kt+1)*8192 + kOff[i], &Kbuf[nxt][(w*4 + i)*512]);
        gl_lds16(Vb + (size_t)(kt+1)*32   + vOff[i], &Vbuf[nxt][(w*4 + i)*512]);
      }
    }
    const ushort* Kc = &Kbuf[cur][0];
    const ushort* Vc = &Vbuf[cur][0];

    // ---- S = Qhat @ K^T : each Ks B-frag feeds both q-sets ---------------
    f32x4 sf[2][2];                          // [set][nt]
    #pragma unroll
    for (int s = 0; s < 2; s++)
      #pragma unroll
      for (int nt = 0; nt < 2; nt++) sf[s][nt] = (f32x4){0.f, 0.f, 0.f, 0.f};
    #pragma unroll
    for (int nt = 0; nt < 2; nt++){
      const ushort* Kr = Kc + nt*4096 + l16*256;
      #pragma unroll
      for (int ks = 0; ks < 8; ks++){
        bf16x8 bfr = *(const bf16x8*)(Kr + kslot[ks]);
        sf[0][nt] = __builtin_amdgcn_mfma_f32_16x16x32_bf16(qf[0][ks], bfr, sf[0][nt], 0,0,0);
        sf[1][nt] = __builtin_amdgcn_mfma_f32_16x16x32_bf16(qf[1][ks], bfr, sf[1][nt], 0,0,0);
      }
    }

    // ---- fixed-M softmax: p = exp2(s - 16); no cross-lane, no rescale ----
    #pragma unroll
    for (int s = 0; s < 2; s++){
      #pragma unroll
      for (int r = 0; r < 4; r++){
        float p0 = exp2f(sf[s][0][r] - FIXED_M);
        float p1 = exp2f(sf[s][1][r] - FIXED_M);
        l_i[s][r] += p0 + p1;
        Ps[w*32 + s*16 + quad*4 + r][l16]      = f2b(p0);
        Ps[w*32 + s*16 + quad*4 + r][16 + l16] = f2b(p1);
      }
    }
    // wave-private LDS round-trip: same-wave ds ordering via lgkmcnt.

    // ---- PV: each Vs B-frag feeds both q-sets ----------------------------
    bf16x8 pf0 = *(const bf16x8*)&Ps[w*32 +      l16][quad*8];
    bf16x8 pf1 = *(const bf16x8*)&Ps[w*32 + 16 + l16][quad*8];
    #pragma unroll
    for (int dt = 0; dt < 16; dt++){
      bf16x8 vf = *(const bf16x8*)(Vc + dt*512 + vlane);  // B[k][n]=V[key][d]
      of[0][dt] = __builtin_amdgcn_mfma_f32_16x16x32_bf16(pf0, vf, of[0][dt], 0, 0, 0);
      of[1][dt] = __builtin_amdgcn_mfma_f32_16x16x32_bf16(pf1, vf, of[1][dt], 0, 0, 0);
    }

    __syncthreads();   // drains prefetch (vmcnt0) + fences buffer swap
    cur = nxt;
  }

  // ---- one l reduction for the whole kernel ------------------------------
  #pragma unroll
  for (int s = 0; s < 2; s++)
    #pragma unroll
    for (int r = 0; r < 4; r++){
      float rs = l_i[s][r];
      #pragma unroll
      for (int msk = 1; msk < 16; msk <<= 1) rs += __shfl_xor(rs, msk, 16);
      l_i[s][r] = rs;
    }

  // ---- epilogue: write unnormalized O-hat + l partials -------------------
  #pragma unroll
  for (int s = 0; s < 2; s++){
    int gq0 = b*4096 + qt*128 + w*32 + s*16 + quad*4;  // global q row, r=0
    if (l16 == 0){
      #pragma unroll
      for (int r = 0; r < 4; r++)
        lp[(size_t)half*16384 + gq0 + r] = l_i[s][r];
    }
    if (half == 0){
      #pragma unroll
      for (int dt = 0; dt < 16; dt++)
        #pragma unroll
        for (int r = 0; r < 4; r++)
          O0[(size_t)(gq0 + r)*256 + dt*16 + l16] = of[s][dt][r];
    } else {
      ushort* Oh = Obf + (size_t)(half - 1)*16384*256;
      #pragma unroll
      for (int dt = 0; dt < 16; dt++)
        #pragma unroll
        for (int r = 0; r < 4; r++)
          Oh[(size_t)(gq0 + r)*256 + dt*16 + l16] = f2b(of[s][dt][r]);
    }
  }
}

// ---------------------------------------------------------------------------
// Merge the 4 split-K partials (all on scale 2^-16), in place over O0.
// out = (O0hat + sum_h Ohat_h) / sum_h l_h.
// ---------------------------------------------------------------------------
__global__ __launch_bounds__(256) void merge_kernel(
    float* __restrict__ O0, const ushort* __restrict__ Obf,
    const float* __restrict__ lp){
  int t   = blockIdx.x*256 + threadIdx.x;    // 0 .. 1048575
  int row = t >> 6;                          // 16384 q rows
  int c   = (t & 63) * 4;
  float den = lp[row] + lp[16384 + row] + lp[2*16384 + row] + lp[3*16384 + row];
  float rden = 1.0f / den;
  size_t idx = (size_t)row*256 + c;
  float4 acc = *(float4*)&O0[idx];
  #pragma unroll
  for (int h = 1; h < 4; h++){
    ushort4 oh = *(const ushort4*)&Obf[(size_t)(h-1)*16384*256 + idx];
    acc.x += b2f(oh.x); acc.y += b2f(oh.y);
    acc.z += b2f(oh.z); acc.w += b2f(oh.w);
  }
  acc.x *= rden; acc.y *= rden; acc.z *= rden; acc.w *= rden;
  *(float4*)&O0[idx] = acc;
}

// ---------------------------------------------------------------------------
extern "C" void kernel_launch(void* const* d_in, const int* in_sizes, int n_in,
                              void* d_out, int out_size, void* d_ws, size_t ws_size,
                              hipStream_t stream){
  const float* x  = (const float*)d_in[0];
  const float* Wk = (const float*)d_in[1];
  const float* bk = (const float*)d_in[2];
  const float* Wq = (const float*)d_in[3];
  const float* bq = (const float*)d_in[4];
  const float* Wv = (const float*)d_in[5];
  const float* bv = (const float*)d_in[6];

  char* ws = (char*)d_ws;
  ushort* Wt  = (ushort*)(ws);                       // 3 x 256 x 256 bf16
  ushort* Qb  = (ushort*)(ws + (size_t)1*(1u<<20));  // 16384 x 256 bf16
  ushort* Kb  = (ushort*)(ws + (size_t)10*(1u<<20));
  ushort* Vtb = (ushort*)(ws + (size_t)19*(1u<<20)); // 4 x 256 x 4096 bf16
  ushort* Obf = (ushort*)(ws + (size_t)28*(1u<<20)); // 3 x 16384 x 256 bf16
  float*  lp  = (float*)(ws + (size_t)54*(1u<<20));  // [4][16384] fp32

  hipLaunchKernelGGL(transpose_w_kernel, dim3(16, 3), dim3(256), 0, stream,
                     Wk, Wq, Wv, Wt);
  hipLaunchKernelGGL(proj_kernel, dim3(256, 3), dim3(256), 0, stream,
                     x, Wt, bk, bq, bv, Kb, Qb, Vtb);
  hipLaunchKernelGGL(attn_kernel, dim3(512), dim3(256), 0, stream,
                     Qb, Kb, Vtb, (float*)d_out, Obf, lp);
  hipLaunchKernelGGL(merge_kernel, dim3(4096), dim3(256), 0, stream,
                     (float*)d_out, Obf, lp);
}

// Round 11
// 203.311 us; speedup vs baseline: 3.1416x; 1.1451x over previous
//
#include <hip/hip_runtime.h>
#include <hip/hip_bf16.h>

// ============================================================================
// SelfAttention B=4, N=4096, D=256.  Inputs fp32, OUTPUT fp32.
//
// R11: (a) proj reverted to LDS-staged W but with register-staged double
// buffer: W(nt+1) global loads issue BEFORE nt's MFMAs (latency hidden),
// ds_write after, ONE barrier per nt (R7 had 2, fully exposed).
// (b) attn softmax fast-pack: f2b (4 ops/val) -> add 0x8000 + v_perm pack
// (1.5 ops/val).  attn otherwise = R10 (async dbuf global_load_lds staging,
// XOR-swizzled unpadded K/V buffers, fixed-M softmax, split-K x4).
// R10 lesson: VGPR budget is EXACTLY full (128 VGPR + 128 AGPR acc = 256) —
// no register-resident V/K variants possible at 2 waves/SIMD.
//
// ws layout (MB): Wt@0 | Q@1 | K@10 | Vt@19 | Obf@28 (3 x 8.4) | lp@54
// ============================================================================

typedef __attribute__((ext_vector_type(8))) short bf16x8;   // MFMA A/B frag (4 VGPR)
typedef __attribute__((ext_vector_type(4))) float f32x4;    // MFMA C/D frag

__device__ __forceinline__ float b2f(ushort u){
  union { uint i; float f; } v; v.i = ((uint)u) << 16; return v.f;
}
__device__ __forceinline__ ushort f2b(float f){             // round-to-nearest-even
  union { float f; uint i; } v; v.f = f;
  uint i = v.i;
  return (ushort)((i + 0x7FFFu + ((i >> 16) & 1u)) >> 16);
}
__device__ __forceinline__ uint pack2(float a, float b){
  return (uint)f2b(a) | ((uint)f2b(b) << 16);
}
__device__ __forceinline__ uint fbits(float f){
  union { float f; uint i; } v; v.f = f; return v.i;
}

// async 16B global -> LDS (DMA; LDS dest = wave-uniform base + lane*16)
__device__ __forceinline__ void gl_lds16(const ushort* g, ushort* l){
  __builtin_amdgcn_global_load_lds(
      (const __attribute__((address_space(1))) uint*)g,
      (__attribute__((address_space(3))) uint*)l, 16, 0, 0);
}

// log2(e)/sqrt(256) = 1.4426950408889634/16
#define Q_SCALE 0.0901684400555602f
#define FIXED_M 16.0f

// ---------------------------------------------------------------------------
// W transpose + fp32->bf16: dst[e][d] = (bf16)src[d][e], src is 256x256 fp32.
// ---------------------------------------------------------------------------
__global__ __launch_bounds__(256) void transpose_w_kernel(
    const float* __restrict__ Wk, const float* __restrict__ Wq,
    const float* __restrict__ Wv, ushort* __restrict__ Wt){
  __shared__ ushort t[64][72];                 // +8 pad
  const float* src = (blockIdx.y == 0) ? Wk : (blockIdx.y == 1) ? Wq : Wv;
  ushort* dst = Wt + blockIdx.y * 65536;
  int tile = blockIdx.x;
  int tr = tile >> 2, tc = tile & 3;           // 4x4 tiles of 64x64
  int tid = threadIdx.x;
  for (int i = tid; i < 1024; i += 256){       // 64 rows x 16 chunks of 4 floats
    int r = i >> 4, ch = i & 15;
    float4 f = *(const float4*)(src + (tr*64 + r)*256 + tc*64 + ch*4);
    uint2 u; u.x = pack2(f.x, f.y); u.y = pack2(f.z, f.w);
    *(uint2*)&t[r][ch*4] = u;
  }
  __syncthreads();
  for (int i = tid; i < 2048; i += 256){       // 64 cols x 32 row-pairs
    int c = i >> 5, r2 = (i & 31)*2;
    uint v = (uint)t[r2][c] | ((uint)t[r2+1][c] << 16);
    *(uint*)(dst + (tc*64 + c)*256 + tr*64 + r2) = v;  // coalesced 4B stores
  }
}

// ---------------------------------------------------------------------------
// QKV projection, register-staged W double-buffer, ONE barrier per nt:
//   loop nt: load W(nt+1)->regs; MFMAs(nt) from wt[cu]; store out(nt);
//            ds_write regs->wt[cu^1]; barrier.
// blockIdx.y: 0=K, 1=Q (scaled), 2=V->Vt transposed.  64 rows/block, K=256.
// LDS 50.7KB -> 3 blocks/CU.
// ---------------------------------------------------------------------------
__global__ __launch_bounds__(256) void proj_kernel(
    const float* __restrict__ x, const ushort* __restrict__ Wt,
    const float* __restrict__ bK, const float* __restrict__ bQ,
    const float* __restrict__ bV,
    ushort* __restrict__ Ko, ushort* __restrict__ Qo, ushort* __restrict__ Vt){
  __shared__ ushort xs[64][264];      // A tile (bf16), +8 pad
  __shared__ ushort wt[2][16][264];   // B tile double buffer
  int my = blockIdx.y;
  int n0 = blockIdx.x * 64;
  const ushort* wsrc = Wt + my*65536;
  const float* bias  = (my==0) ? bK : (my==1) ? bQ : bV;

  int tid = threadIdx.x;
  int lane = tid & 63, w = tid >> 6, quad = lane >> 4, l16 = lane & 15;

  for (int i = tid; i < 4096; i += 256){       // stage x: 64 rows x 64 f4-chunks
    int r = i >> 6, ch = i & 63;
    float4 f = *(const float4*)(x + (size_t)(n0 + r)*256 + ch*4);
    uint2 u; u.x = pack2(f.x, f.y); u.y = pack2(f.z, f.w);
    *(uint2*)&xs[r][ch*4] = u;
  }

  // per-thread W staging slots: 2 x 16B of the 8KB tile
  int seg0 = tid*2,     r0 = seg0 >> 5, c0 = seg0 & 31;
  int seg1 = tid*2 + 1, r1 = seg1 >> 5, c1 = seg1 & 31;
  {                                            // prologue: stage W(0) -> wt[0]
    uint4 a = *(const uint4*)(wsrc + r0*256 + c0*8);
    uint4 b = *(const uint4*)(wsrc + r1*256 + c1*8);
    *(uint4*)&wt[0][r0][c0*8] = a;
    *(uint4*)&wt[0][r1][c1*8] = b;
  }
  __syncthreads();

  bf16x8 afr[8];                               // wave's 16 rows, all of K=256
  #pragma unroll
  for (int ks = 0; ks < 8; ks++)
    afr[ks] = *(const bf16x8*)&xs[w*16 + l16][ks*32 + quad*8];

  for (int nt = 0; nt < 16; nt++){
    int cu = nt & 1;
    uint4 wa, wb;
    if (nt < 15){                              // load W(nt+1) early (hidden)
      const ushort* wn = wsrc + (nt+1)*4096;
      wa = *(const uint4*)(wn + r0*256 + c0*8);
      wb = *(const uint4*)(wn + r1*256 + c1*8);
    }
    f32x4 acc = {0.f, 0.f, 0.f, 0.f};
    #pragma unroll
    for (int ks = 0; ks < 8; ks++){
      bf16x8 bfr = *(const bf16x8*)&wt[cu][l16][ks*32 + quad*8];
      acc = __builtin_amdgcn_mfma_f32_16x16x32_bf16(afr[ks], bfr, acc, 0, 0, 0);
    }
    int e = nt*16 + l16;
    float bv = bias[e];
    if (my == 2){                              // V: write transposed Vt[b][e][n]
      int b  = n0 >> 12;
      int nl = (n0 & 4095) + w*16 + quad*4;    // n within batch
      ushort* vb = Vt + (size_t)b*1048576 + (size_t)e*4096 + nl;
      #pragma unroll
      for (int r = 0; r < 4; r++) vb[r] = f2b(acc[r] + bv);
    } else {
      float scale = (my==1) ? Q_SCALE : 1.0f;
      ushort* out = (my==0) ? Ko : Qo;
      #pragma unroll
      for (int r = 0; r < 4; r++){
        int row = n0 + w*16 + quad*4 + r;      // C layout: row=quad*4+r, col=l16
        out[(size_t)row*256 + e] = f2b((acc[r] + bv) * scale);
      }
    }
    if (nt < 15){                              // commit W(nt+1) to wt[cu^1]
      *(uint4*)&wt[cu^1][r0][c0*8] = wa;
      *(uint4*)&wt[cu^1][r1][c1*8] = wb;
    }
    __syncthreads();
  }
}

// ---------------------------------------------------------------------------
// Flash attention, split-K x4, 2 q-sets/wave, fixed-M softmax, async dbuf.
// 512 blocks: bx & 15 = (b<<2)|half ; bx >> 4 = qt 0..31 (128 q/tile).
// kt loop: stage(kt+1 -> buf[nxt]) async; compute(kt) on buf[cur]; ONE
// __syncthreads (drains prefetch, fences buffer swap).
// Softmax pack: add 0x8000 + v_perm (round-half-up bf16 pair per op).
// Writes UNNORMALIZED O-hat + l: half 0 -> O0 (fp32, = d_out),
// halves 1..3 -> Obf (bf16, ws).  All partials share scale 2^-16.
// ---------------------------------------------------------------------------
__global__ __launch_bounds__(256, 2) void attn_kernel(
    const ushort* __restrict__ Q, const ushort* __restrict__ K,
    const ushort* __restrict__ Vt,
    float* __restrict__ O0, ushort* __restrict__ Obf, float* __restrict__ lp){
  __shared__ ushort Kbuf[2][8192];   // 32 keys x 256 d, unpadded+swizzled
  __shared__ ushort Vbuf[2][8192];   // 256 d x 32 keys, unpadded+swizzled
  __shared__ ushort Ps[128][40];     // P round-trip, wave-private rows

  int bx   = blockIdx.x;
  int bh   = bx & 15;
  int b    = bh >> 2;                       // batch 0..3
  int half = bh & 3;                        // k-quarter 0..3
  int qt   = bx >> 4;                       // q-tile 0..31 (128 q each)
  int tid = threadIdx.x, lane = tid & 63, w = tid >> 6;
  int quad = lane >> 4, l16 = lane & 15;

  const ushort* Qb = Q  + (size_t)(b*4096 + qt*128)*256;
  const ushort* Kb = K  + (size_t)b*4096*256;
  const ushort* Vb = Vt + (size_t)b*256*4096;

  // ---- staging lane->global offset precompute (swizzled) -----------------
  int kOff[4], vOff[4];
  #pragma unroll
  for (int i = 0; i < 4; i++){
    int off16 = (w*4 + i)*64 + lane;         // 16B unit within 16KB tile
    int krow = off16 >> 5, ks_ = off16 & 31;
    int g    = ks_ ^ (krow & 7);             // K swizzle: chunk stored at slot
    kOff[i]  = krow*256 + g*8;               // ushort offset in K global tile
    int sr = off16 >> 3, sl = off16 & 7;     // V: 128B superrow, 16B slot
    int xv = sl ^ (sr & 7);
    int d  = sr*2 + ((xv >> 2) & 1), c = xv & 3;
    vOff[i] = d*4096 + c*8;                  // ushort offset (Vt row stride 4096)
  }
  // compute-side swizzled read offsets
  int m7 = l16 & 7;
  int kslot[8];
  #pragma unroll
  for (int ks = 0; ks < 8; ks++) kslot[ks] = ((ks*4 + quad) ^ m7) * 8;
  int vlane = (((l16 >> 1)*8) + (((l16 & 1)*4 + quad) ^ (l16 >> 1))) * 8;

  bf16x8 qf[2][8];                 // A-frags, 2 sets: rows w*32+s*16+l16
  #pragma unroll
  for (int s = 0; s < 2; s++)
    #pragma unroll
    for (int ks = 0; ks < 8; ks++)
      qf[s][ks] = *(const bf16x8*)(Qb + (size_t)(w*32 + s*16 + l16)*256 + ks*32 + quad*8);

  f32x4 of[2][16];                 // O accumulators
  #pragma unroll
  for (int s = 0; s < 2; s++)
    #pragma unroll
    for (int dt = 0; dt < 16; dt++) of[s][dt] = (f32x4){0.f, 0.f, 0.f, 0.f};
  float l_i[2][4];                 // per-LANE partial sums (2 cols each)
  #pragma unroll
  for (int s = 0; s < 2; s++)
    #pragma unroll
    for (int r = 0; r < 4; r++) l_i[s][r] = 0.f;

  int kt0 = half * 32, kt1 = kt0 + 32;

  // ---- prologue: stage kt0 into buf 0, drain ----------------------------
  #pragma unroll
  for (int i = 0; i < 4; i++){
    gl_lds16(Kb + (size_t)kt0*8192 + kOff[i], &Kbuf[0][(w*4 + i)*512]);
    gl_lds16(Vb + (size_t)kt0*32   + vOff[i], &Vbuf[0][(w*4 + i)*512]);
  }
  __syncthreads();

  int cur = 0;
  for (int kt = kt0; kt < kt1; kt++){
    int nxt = cur ^ 1;
    if (kt + 1 < kt1){                       // async prefetch kt+1 -> buf[nxt]
      #pragma unroll
      for (int i = 0; i < 4; i++){
        gl_lds16(Kb + (size_t)(kt+1)*8192 + kOff[i], &Kbuf[nxt][(w*4 + i)*512]);
        gl_lds16(Vb + (size_t)(kt+1)*32   + vOff[i], &Vbuf[nxt][(w*4 + i)*512]);
      }
    }
    const ushort* Kc = &Kbuf[cur][0];
    const ushort* Vc = &Vbuf[cur][0];

    // ---- S = Qhat @ K^T : each Ks B-frag feeds both q-sets ---------------
    f32x4 sf[2][2];                          // [set][nt]
    #pragma unroll
    for (int s = 0; s < 2; s++)
      #pragma unroll
      for (int nt = 0; nt < 2; nt++) sf[s][nt] = (f32x4){0.f, 0.f, 0.f, 0.f};
    #pragma unroll
    for (int nt = 0; nt < 2; nt++){
      const ushort* Kr = Kc + nt*4096 + l16*256;
      #pragma unroll
      for (int ks = 0; ks < 8; ks++){
        bf16x8 bfr = *(const bf16x8*)(Kr + kslot[ks]);
        sf[0][nt] = __builtin_amdgcn_mfma_f32_16x16x32_bf16(qf[0][ks], bfr, sf[0][nt], 0,0,0);
        sf[1][nt] = __builtin_amdgcn_mfma_f32_16x16x32_bf16(qf[1][ks], bfr, sf[1][nt], 0,0,0);
      }
    }

    // ---- fixed-M softmax: p = exp2(s-16); fast bf16 pack (round-half-up) -
    #pragma unroll
    for (int s = 0; s < 2; s++){
      #pragma unroll
      for (int r = 0; r < 4; r++){
        float p0 = exp2f(sf[s][0][r] - FIXED_M);
        float p1 = exp2f(sf[s][1][r] - FIXED_M);
        l_i[s][r] += p0 + p1;
        uint pb = __builtin_amdgcn_perm(fbits(p1) + 0x8000u,
                                        fbits(p0) + 0x8000u, 0x07060302u);
        ushort* prow = &Ps[w*32 + s*16 + quad*4 + r][0];
        prow[l16]      = (ushort)pb;
        prow[16 + l16] = (ushort)(pb >> 16);
      }
    }
    // wave-private LDS round-trip: same-wave ds ordering via lgkmcnt.

    // ---- PV: each Vs B-frag feeds both q-sets ----------------------------
    bf16x8 pf0 = *(const bf16x8*)&Ps[w*32 +      l16][quad*8];
    bf16x8 pf1 = *(const bf16x8*)&Ps[w*32 + 16 + l16][quad*8];
    #pragma unroll
    for (int dt = 0; dt < 16; dt++){
      bf16x8 vf = *(const bf16x8*)(Vc + dt*512 + vlane);  // B[k][n]=V[key][d]
      of[0][dt] = __builtin_amdgcn_mfma_f32_16x16x32_bf16(pf0, vf, of[0][dt], 0, 0, 0);
      of[1][dt] = __builtin_amdgcn_mfma_f32_16x16x32_bf16(pf1, vf, of[1][dt], 0, 0, 0);
    }

    __syncthreads();   // drains prefetch (vmcnt0) + fences buffer swap
    cur = nxt;
  }

  // ---- one l reduction for the whole kernel ------------------------------
  #pragma unroll
  for (int s = 0; s < 2; s++)
    #pragma unroll
    for (int r = 0; r < 4; r++){
      float rs = l_i[s][r];
      #pragma unroll
      for (int msk = 1; msk < 16; msk <<= 1) rs += __shfl_xor(rs, msk, 16);
      l_i[s][r] = rs;
    }

  // ---- epilogue: write unnormalized O-hat + l partials -------------------
  #pragma unroll
  for (int s = 0; s < 2; s++){
    int gq0 = b*4096 + qt*128 + w*32 + s*16 + quad*4;  // global q row, r=0
    if (l16 == 0){
      #pragma unroll
      for (int r = 0; r < 4; r++)
        lp[(size_t)half*16384 + gq0 + r] = l_i[s][r];
    }
    if (half == 0){
      #pragma unroll
      for (int dt = 0; dt < 16; dt++)
        #pragma unroll
        for (int r = 0; r < 4; r++)
          O0[(size_t)(gq0 + r)*256 + dt*16 + l16] = of[s][dt][r];
    } else {
      ushort* Oh = Obf + (size_t)(half - 1)*16384*256;
      #pragma unroll
      for (int dt = 0; dt < 16; dt++)
        #pragma unroll
        for (int r = 0; r < 4; r++)
          Oh[(size_t)(gq0 + r)*256 + dt*16 + l16] = f2b(of[s][dt][r]);
    }
  }
}

// ---------------------------------------------------------------------------
// Merge the 4 split-K partials (all on scale 2^-16), in place over O0.
// out = (O0hat + sum_h Ohat_h) / sum_h l_h.
// ---------------------------------------------------------------------------
__global__ __launch_bounds__(256) void merge_kernel(
    float* __restrict__ O0, const ushort* __restrict__ Obf,
    const float* __restrict__ lp){
  int t   = blockIdx.x*256 + threadIdx.x;    // 0 .. 1048575
  int row = t >> 6;                          // 16384 q rows
  int c   = (t & 63) * 4;
  float den = lp[row] + lp[16384 + row] + lp[2*16384 + row] + lp[3*16384 + row];
  float rden = 1.0f / den;
  size_t idx = (size_t)row*256 + c;
  float4 acc = *(float4*)&O0[idx];
  #pragma unroll
  for (int h = 1; h < 4; h++){
    ushort4 oh = *(const ushort4*)&Obf[(size_t)(h-1)*16384*256 + idx];
    acc.x += b2f(oh.x); acc.y += b2f(oh.y);
    acc.z += b2f(oh.z); acc.w += b2f(oh.w);
  }
  acc.x *= rden; acc.y *= rden; acc.z *= rden; acc.w *= rden;
  *(float4*)&O0[idx] = acc;
}

// ---------------------------------------------------------------------------
extern "C" void kernel_launch(void* const* d_in, const int* in_sizes, int n_in,
                              void* d_out, int out_size, void* d_ws, size_t ws_size,
                              hipStream_t stream){
  const float* x  = (const float*)d_in[0];
  const float* Wk = (const float*)d_in[1];
  const float* bk = (const float*)d_in[2];
  const float* Wq = (const float*)d_in[3];
  const float* bq = (const float*)d_in[4];
  const float* Wv = (const float*)d_in[5];
  const float* bv = (const float*)d_in[6];

  char* ws = (char*)d_ws;
  ushort* Wt  = (ushort*)(ws);                       // 3 x 256 x 256 bf16
  ushort* Qb  = (ushort*)(ws + (size_t)1*(1u<<20));  // 16384 x 256 bf16
  ushort* Kb  = (ushort*)(ws + (size_t)10*(1u<<20));
  ushort* Vtb = (ushort*)(ws + (size_t)19*(1u<<20)); // 4 x 256 x 4096 bf16
  ushort* Obf = (ushort*)(ws + (size_t)28*(1u<<20)); // 3 x 16384 x 256 bf16
  float*  lp  = (float*)(ws + (size_t)54*(1u<<20));  // [4][16384] fp32

  hipLaunchKernelGGL(transpose_w_kernel, dim3(16, 3), dim3(256), 0, stream,
                     Wk, Wq, Wv, Wt);
  hipLaunchKernelGGL(proj_kernel, dim3(256, 3), dim3(256), 0, stream,
                     x, Wt, bk, bq, bv, Kb, Qb, Vtb);
  hipLaunchKernelGGL(attn_kernel, dim3(512), dim3(256), 0, stream,
                     Qb, Kb, Vtb, (float*)d_out, Obf, lp);
  hipLaunchKernelGGL(merge_kernel, dim3(4096), dim3(256), 0, stream,
                     (float*)d_out, Obf, lp);
}